// Round 7
// baseline (18.764 us; speedup 1.0000x reference)
//
#include <hip/hip_runtime.h>

// A (256, 512, 2) f32, B (2, 1024) f32, out (256, 1) f32.
constexpr int BATCH  = 256;
constexpr int MAXLEN = 512;
constexpr int LENF   = 1024;

typedef float f2 __attribute__((ext_vector_type(2)));

// out[b] = bump( max_c min_{l,j} q(l, c + j*512) ),  c in [0,512), j in {0,1}
//   q(l,f) = max(|A[b,l,0]-B[0,f]|, |A[b,l,1]-B[1,f]|)
//   bump(t) = e/(1+e)^2, e = exp(-10 t)
// (math verified absmax==0 in R1..R6)
//
// Single dispatch: 256 blocks (1/batch) x 1024 threads = 16 waves/CU.
// Thread (c, h): c-pair c, l-half h (readfirstlane -> SGPR -> uniform A
// slice -> s_load; R4 lesson). R7 change: explicit software pipeline on the
// scalar A stream — prefetch the next 8-element group (2x s_load_dwordx8)
// while computing the current one (40 VALU ops), so waves never stall on
// lgkmcnt at group boundaries. 8 independent min chains (ILP 8).
__global__ __launch_bounds__(1024)
void chebbump_kernel(const float* __restrict__ A,
                     const float* __restrict__ B,
                     float* __restrict__ out)
{
    const int b = blockIdx.x;
    const int t = threadIdx.x;
    const int c = t & (MAXLEN - 1);                        // c in [0, 512)
    const int h = __builtin_amdgcn_readfirstlane(t >> 9);  // l-half, SGPR

    // Uniform A slice for this half: 256 (a0,a1) pairs -> scalar loads.
    const f2* __restrict__ A2 =
        reinterpret_cast<const f2*>(A + (size_t)b * (MAXLEN * 2)) + h * (MAXLEN / 2);

    // This thread's two B columns (f = c and f = c + 512), coalesced.
    const f2 bc = { B[c],          B[LENF + c] };
    const f2 bd = { B[MAXLEN + c], B[LENF + MAXLEN + c] };

    float u[8];
#pragma unroll
    for (int k = 0; k < 8; ++k) u[k] = 3.4e38f;

    // Prologue: load group 0 into cur.
    f2 cur[8], nxt[8];
#pragma unroll
    for (int k = 0; k < 8; ++k) cur[k] = A2[k];

    // Pipelined main loop: prefetch group g+1, compute group g.
    for (int l = 8; l < MAXLEN / 2; l += 8) {
#pragma unroll
        for (int k = 0; k < 8; ++k) nxt[k] = A2[l + k];
#pragma unroll
        for (int k = 0; k < 8; ++k) {
            const f2 dc = cur[k] - bc;   // v_pk_add_f32 (neg mod), SGPR src
            const f2 dd = cur[k] - bd;
            u[k] = fminf(u[k], fminf(fmaxf(fabsf(dc.x), fabsf(dc.y)),
                                     fmaxf(fabsf(dd.x), fabsf(dd.y))));
        }
#pragma unroll
        for (int k = 0; k < 8; ++k) cur[k] = nxt[k];
    }
    // Epilogue: compute the last group.
#pragma unroll
    for (int k = 0; k < 8; ++k) {
        const f2 dc = cur[k] - bc;
        const f2 dd = cur[k] - bd;
        u[k] = fminf(u[k], fminf(fmaxf(fabsf(dc.x), fabsf(dc.y)),
                                 fmaxf(fabsf(dd.x), fabsf(dd.y))));
    }

    float v = fminf(fminf(fminf(u[0], u[1]), fminf(u[2], u[3])),
                    fminf(fminf(u[4], u[5]), fminf(u[6], u[7])));

    // Join the two l-halves of each c (min), then block-wide max over c.
    __shared__ float su[1024];
    __shared__ float sw[8];
    su[t] = v;
    __syncthreads();
    if (t < MAXLEN) {
        v = fminf(su[t], su[t + MAXLEN]);   // join l-halves
#pragma unroll
        for (int off = 32; off > 0; off >>= 1)
            v = fmaxf(v, __shfl_xor(v, off));   // 64-lane wave max
        if ((t & 63) == 0) sw[t >> 6] = v;
    }
    __syncthreads();

    if (t == 0) {
        float m = sw[0];
#pragma unroll
        for (int i = 1; i < 8; ++i) m = fmaxf(m, sw[i]);
        const float e = expf(-10.0f * m);   // m >= 0, e <= 1: stable
        const float d = 1.0f + e;
        out[b] = e / (d * d);               // sigmoid(10t)*sigmoid(-10t)
    }
}

extern "C" void kernel_launch(void* const* d_in, const int* in_sizes, int n_in,
                              void* d_out, int out_size, void* d_ws, size_t ws_size,
                              hipStream_t stream)
{
    const float* A = (const float*)d_in[0];
    const float* B = (const float*)d_in[1];
    float* out = (float*)d_out;

    hipLaunchKernelGGL(chebbump_kernel, dim3(BATCH), dim3(1024), 0, stream,
                       A, B, out);
}

// Round 8
// 18.224 us; speedup vs baseline: 1.0296x; 1.0296x over previous
//
#include <hip/hip_runtime.h>

// A (256, 512, 2) f32, B (2, 1024) f32, out (256, 1) f32.
constexpr int BATCH  = 256;
constexpr int MAXLEN = 512;
constexpr int LENF   = 1024;

typedef float f2 __attribute__((ext_vector_type(2)));

// out[b] = bump( max_c min_{l,j} q(l, c + j*512) ),  c in [0,512), j in {0,1}
//   q(l,f) = max(|A[b,l,0]-B[0,f]|, |A[b,l,1]-B[1,f]|)
//   bump(t) = e/(1+e)^2, e = exp(-10 t)
// (math verified absmax==0 in R1..R7)
//
// Final form (R6, best measured 18.23 us ~= 14 us fixed graph overhead +
// 4.3 us VALU floor):
// - Single dispatch: 256 blocks (1/batch) x 1024 threads = 16 waves/CU.
// - Thread (c, h): c-pair c, l-half h. readfirstlane(t>>9) puts h in an
//   SGPR so the A slice stays provably uniform -> s_load broadcast (the
//   R4 lesson: threadIdx-derived addressing demotes to per-lane vmem).
// - Inner body: float2 ext-vector subs -> v_pk_add_f32; fabs folds into
//   VOP3 abs modifiers; fminf(u, fminf(q1,q2)) -> v_min3_f32.
//   5 VALU ops per (l, c-pair) covering both paired f columns — minimal
//   for the exact computation (4 distinct subtractions required).
// - 4 independent min chains hide the v_min dependency spine.
__global__ __launch_bounds__(1024)
void chebbump_kernel(const float* __restrict__ A,
                     const float* __restrict__ B,
                     float* __restrict__ out)
{
    const int b = blockIdx.x;
    const int t = threadIdx.x;
    const int c = t & (MAXLEN - 1);                        // c in [0, 512)
    const int h = __builtin_amdgcn_readfirstlane(t >> 9);  // l-half, SGPR

    // Uniform A slice for this half: 256 (a0,a1) pairs -> scalar loads.
    const f2* __restrict__ A2 =
        reinterpret_cast<const f2*>(A + (size_t)b * (MAXLEN * 2)) + h * (MAXLEN / 2);

    // This thread's two B columns (f = c and f = c + 512), coalesced.
    const f2 bc = { B[c],          B[LENF + c] };
    const f2 bd = { B[MAXLEN + c], B[LENF + MAXLEN + c] };

    // 4 independent min chains over this half's 256 l values.
    float u0 = 3.4e38f, u1 = 3.4e38f, u2 = 3.4e38f, u3 = 3.4e38f;
#pragma unroll 4
    for (int l = 0; l < MAXLEN / 2; l += 4) {
        const f2 a0 = A2[l + 0];
        const f2 a1 = A2[l + 1];
        const f2 a2 = A2[l + 2];
        const f2 a3 = A2[l + 3];
        const f2 d0c = a0 - bc, d0d = a0 - bd;   // v_pk_add_f32 (neg mod)
        const f2 d1c = a1 - bc, d1d = a1 - bd;
        const f2 d2c = a2 - bc, d2d = a2 - bd;
        const f2 d3c = a3 - bc, d3d = a3 - bd;
        u0 = fminf(u0, fminf(fmaxf(fabsf(d0c.x), fabsf(d0c.y)),
                             fmaxf(fabsf(d0d.x), fabsf(d0d.y))));
        u1 = fminf(u1, fminf(fmaxf(fabsf(d1c.x), fabsf(d1c.y)),
                             fmaxf(fabsf(d1d.x), fabsf(d1d.y))));
        u2 = fminf(u2, fminf(fmaxf(fabsf(d2c.x), fabsf(d2c.y)),
                             fmaxf(fabsf(d2d.x), fabsf(d2d.y))));
        u3 = fminf(u3, fminf(fmaxf(fabsf(d3c.x), fabsf(d3c.y)),
                             fmaxf(fabsf(d3d.x), fabsf(d3d.y))));
    }
    float v = fminf(fminf(u0, u1), fminf(u2, u3));

    // Join the two l-halves of each c (min), then block-wide max over c.
    __shared__ float su[1024];
    __shared__ float sw[8];
    su[t] = v;
    __syncthreads();
    if (t < MAXLEN) {
        v = fminf(su[t], su[t + MAXLEN]);   // join l-halves
#pragma unroll
        for (int off = 32; off > 0; off >>= 1)
            v = fmaxf(v, __shfl_xor(v, off));   // 64-lane wave max
        if ((t & 63) == 0) sw[t >> 6] = v;
    }
    __syncthreads();

    if (t == 0) {
        float m = sw[0];
#pragma unroll
        for (int i = 1; i < 8; ++i) m = fmaxf(m, sw[i]);
        const float e = expf(-10.0f * m);   // m >= 0, e <= 1: stable
        const float d = 1.0f + e;
        out[b] = e / (d * d);               // sigmoid(10t)*sigmoid(-10t)
    }
}

extern "C" void kernel_launch(void* const* d_in, const int* in_sizes, int n_in,
                              void* d_out, int out_size, void* d_ws, size_t ws_size,
                              hipStream_t stream)
{
    const float* A = (const float*)d_in[0];
    const float* B = (const float*)d_in[1];
    float* out = (float*)d_out;

    hipLaunchKernelGGL(chebbump_kernel, dim3(BATCH), dim3(1024), 0, stream,
                       A, B, out);
}